// Round 1
// 567.449 us; speedup vs baseline: 1.0352x; 1.0352x over previous
//
#include <hip/hip_runtime.h>
#include <math.h>

#define BB 32
#define TT 2048
#define VV 1024
#define SS 256

// ---- async global->LDS gather: PER-LANE global addr, wave-uniform LDS base + lane*4 ----
__device__ __forceinline__ void async_ld4(const float* g, const float* l) {
    __builtin_amdgcn_global_load_lds(
        (const __attribute__((address_space(1))) void*)(uintptr_t)g,
        (__attribute__((address_space(3))) void*)(unsigned)(uintptr_t)l, 4, 0, 0);
}
// s_waitcnt simm16: [3:0]=vmcnt lo, [6:4]=expcnt, [11:8]=lgkmcnt, [15:14]=vmcnt hi
#define WAIT_VM33() __builtin_amdgcn_s_waitcnt(0x8F71)  // vmcnt<=33: oldest in-flight chunk landed
#define WAIT_VM0()  __builtin_amdgcn_s_waitcnt(0x0F70)  // vmcnt<=0 drain

// ---- DPP wave_shr1: value from lane-1, lane0 -> 0. One VALU op, no lgkmcnt. ----
__device__ __forceinline__ float dpp_shr1_f(float x) {
    int r = __builtin_amdgcn_update_dpp(0, __float_as_int(x), 0x138, 0xF, 0xF, true);
    return __int_as_float(r);
}
__device__ __forceinline__ int dpp_shr1_i(int x) {
    return __builtin_amdgcn_update_dpp(0, x, 0x138, 0xF, 0xF, true);
}

// Fused CTC: one wave per sample gathers exp-args straight from lp via
// global_load_lds hardware gather (per-lane global addr = row base + token
// offset), double-depth prefetch over 4 LDS slots (33 vm-ops/chunk <= 63
// vmcnt budget), branchless 8-step main chunks, bit-trick renorm.
__global__ __launch_bounds__(64, 1) void ctc_walk(const float* __restrict__ lp,
    const int* __restrict__ tokens, const int* __restrict__ cqt,
    const int* __restrict__ slen, float* __restrict__ out)
{
    __shared__ __align__(16) float tokS[4][8][4][64];  // 32 KB: 4 slots x 8 rows x 4 comps x 64 lanes
    __shared__ __align__(16) float blkS[4][64];        // 1 KB: blank rows (lanes 0..7 carry t..t+7)
    __shared__ float als[513];
    __shared__ int   aE[65];

    const int b    = blockIdx.x;
    const int lane = threadIdx.x;
    const int Tl   = cqt[b];
    const int Sl   = slen[b];
    const float* __restrict__ lpB = lp + (size_t)b * TT * VV;
    const int j0 = lane * 4;
    const int* tb = tokens + b * SS;
    const int tm1 = (j0 == 0) ? 0 : tb[j0 - 1];
    const int q0 = tb[j0], q1 = tb[j0 + 1], q2 = tb[j0 + 2], q3 = tb[j0 + 3];
    const float m0 = (q0 != tm1) ? 1.f : 0.f;
    const float m1 = (q1 != q0)  ? 1.f : 0.f;
    const float m2 = (q2 != q1)  ? 1.f : 0.f;
    const float m3 = (q3 != q2)  ? 1.f : 0.f;
    // z-mask reproduces old G semantics: pe=0 for j >= Sl
    const float z0 = (j0 + 0 < Sl) ? 1.f : 0.f;
    const float z1 = (j0 + 1 < Sl) ? 1.f : 0.f;
    const float z2 = (j0 + 2 < Sl) ? 1.f : 0.f;
    const float z3 = (j0 + 3 < Sl) ? 1.f : 0.f;
    const float lzm = (lane == 0) ? 0.f : 1.f;
    const bool glane = (j0 < Sl);   // Sl >= 128 -> lanes 0..31 always active (EXEC never 0)

    float a0=0.f,a1=0.f,a2=0.f,a3=0.f,a4=0.f,a5=0.f,a6=0.f,a7=0.f,aX=0.f;
    if (lane == 0) { a0 = __expf(lpB[0]); a1 = __expf(lpB[tb[0]]); }  // t=0 init (j=0 < Sl always)
    int   Etot = 0;
    float sfac = lzm;

    // One chunk = 8 rows x 4 token gathers (EXEC-predicated on glane; dead lanes
    // z-masked at consume) + 1 blank gather (lane&7 spans rows t..t+7) = 33 vm ops.
#define ISSUE(s, tbase) do { \
    if (glane) { \
        _Pragma("unroll") \
        for (int k = 0; k < 8; ++k) { \
            int tt = (tbase) + k; tt = (tt < Tl) ? tt : (Tl - 1); \
            const float* rp = lpB + ((size_t)tt << 10); \
            async_ld4(rp + q0, &tokS[s][k][0][0]); \
            async_ld4(rp + q1, &tokS[s][k][1][0]); \
            async_ld4(rp + q2, &tokS[s][k][2][0]); \
            async_ld4(rp + q3, &tokS[s][k][3][0]); \
        } \
    } \
    { int tbk = (tbase) + (lane & 7); tbk = (tbk < Tl) ? tbk : (Tl - 1); \
      async_ld4(lpB + ((size_t)tbk << 10), blkS[s]); } \
} while (0)

#define LOADCHUNK(s) do { \
    _Pragma("unroll") \
    for (int k = 0; k < 8; ++k) { \
        pr[k][0] = tokS[s][k][0][lane]; \
        pr[k][1] = tokS[s][k][1][lane]; \
        pr[k][2] = tokS[s][k][2][lane]; \
        pr[k][3] = tokS[s][k][3][lane]; \
        pb[k]    = blkS[s][k]; \
    } \
} while (0)

#define EXPCHUNK() do { \
    _Pragma("unroll") \
    for (int k = 0; k < 8; ++k) { \
        pr[k][0] = __expf(pr[k][0]) * z0; \
        pr[k][1] = __expf(pr[k][1]) * z1; \
        pr[k][2] = __expf(pr[k][2]) * z2; \
        pr[k][3] = __expf(pr[k][3]) * z3; \
        pb[k]    = __expf(pb[k]); \
    } \
} while (0)

#define ONESTEP(PR, PB) do { \
    const float pb_ = (PB); \
    const float h1 = dpp_shr1_f(a7) * sfac; \
    const float n0 = pb_ * (a0 + h1); \
    const float n1 = (PR)[0] * (a1 + a0 + m0 * h1); \
    const float n2 = pb_ * (a2 + a1); \
    const float n3 = (PR)[1] * (a3 + a2 + m1 * a1); \
    const float n4 = pb_ * (a4 + a3); \
    const float n5 = (PR)[2] * (a5 + a4 + m2 * a3); \
    const float n6 = pb_ * (a6 + a5); \
    const float n7 = (PR)[3] * (a7 + a6 + m3 * a5); \
    aX = pb_ * (aX + a7); \
    a0=n0;a1=n1;a2=n2;a3=n3;a4=n4;a5=n5;a6=n6;a7=n7; \
} while (0)

    // Bit-trick renorm (mm never subnormal: p >= e^-16 over 4 steps keeps mm >= 2^-93).
#define RENORM_LOCAL() do { \
    float mm = fmaxf(fmaxf(fmaxf(a0,a1),fmaxf(a2,a3)), fmaxf(fmaxf(a4,a5),fmaxf(a6,a7))); \
    mm = fmaxf(mm, aX); \
    int ee = (__float_as_int(mm) >> 23) - 126; \
    ee = (mm > 0.f) ? ee : 0; \
    const float sc = __int_as_float((127 - ee) << 23); \
    a0*=sc;a1*=sc;a2*=sc;a3*=sc;a4*=sc;a5*=sc;a6*=sc;a7*=sc;aX*=sc; \
    Etot += ee; \
    int Ep = dpp_shr1_i(Etot); \
    if (mm == 0.f && lane > 0) Etot = Ep; \
    Ep = dpp_shr1_i(Etot); \
    if (mm == 0.f && lane > 0) Etot = Ep; \
    int dd = Ep - Etot; \
    dd = (dd < -126) ? -126 : ((dd > 100) ? 100 : dd); \
    sfac = __int_as_float((127 + dd) << 23) * lzm; \
} while (0)

    float pr[8][4], pb[8];                       // static-index only -> registers

    ISSUE(0, 1);                                 // depth-2 prefetch
    ISSUE(1, 9);
    int t = 1, slot = 0;
    while (t + 8 <= Tl) {                        // branchless full chunks
        WAIT_VM33();                             // chunk for 'slot' landed (newest 33 may fly)
        __builtin_amdgcn_sched_barrier(0);       // no ds_read may float above the wait
        LOADCHUNK(slot);                         // 40 ds_reads batched; latency hides under ISSUE
        ISSUE((slot + 2) & 3, t + 16);           // write slot disjoint from read slot
        EXPCHUNK();                              // off the serial chain, fills stall slots
#pragma unroll
        for (int k = 0; k < 8; ++k) {
            ONESTEP(pr[k], pb[k]);
            if (k == 3 || k == 7) RENORM_LOCAL();
        }
        t += 8; slot = (slot + 1) & 3;
    }
    if (t < Tl) {                                // tail chunk (nv in 1..7), already prefetched
        WAIT_VM33();
        __builtin_amdgcn_sched_barrier(0);
        LOADCHUNK(slot);
        EXPCHUNK();
        const int nv = Tl - t;
#pragma unroll
        for (int k = 0; k < 8; ++k) {
            if (k < nv) ONESTEP(pr[k], pb[k]);
            if (k == 3 || k == 7) RENORM_LOCAL();
        }
    }
    WAIT_VM0();                                  // drain unconsumed prefetch before epilogue

    als[8 * lane + 0] = a0; als[8 * lane + 1] = a1;
    als[8 * lane + 2] = a2; als[8 * lane + 3] = a3;
    als[8 * lane + 4] = a4; als[8 * lane + 5] = a5;
    als[8 * lane + 6] = a6; als[8 * lane + 7] = a7;
    aE[lane] = Etot;
    if (lane == 63) { als[512] = aX; aE[64] = Etot; }
    __syncthreads();
    if (lane == 0) {
        const int sA = 2 * Sl, sB = 2 * Sl - 1;
        const float vA = als[sA], vB = als[sB];
        const int   eA = aE[sA >> 3], eB = aE[sB >> 3];
        int em;
        if (vA > 0.f && vB > 0.f) em = (eA > eB) ? eA : eB;
        else if (vA > 0.f)        em = eA;
        else if (vB > 0.f)        em = eB;
        else                      em = 0;
        const double s = ldexp((double)vA, eA - em) + ldexp((double)vB, eB - em);
        double loss = -(log(s) + (double)em * 0.6931471805599453);
        if (!(loss < 1e29)) loss = 0.0;
        atomicAdd(out, (float)(loss / ((double)Sl * (double)BB)));
    }
#undef ISSUE
#undef LOADCHUNK
#undef EXPCHUNK
#undef ONESTEP
#undef RENORM_LOCAL
}

extern "C" void kernel_launch(void* const* d_in, const int* in_sizes, int n_in,
                              void* d_out, int out_size, void* d_ws, size_t ws_size,
                              hipStream_t stream)
{
    (void)in_sizes; (void)n_in; (void)d_ws; (void)ws_size;
    const float* lp     = (const float*)d_in[0];
    const int*   tokens = (const int*)d_in[1];
    const int*   cqt    = (const int*)d_in[2];
    const int*   slen   = (const int*)d_in[3];
    float* out = (float*)d_out;

    hipMemsetAsync(out, 0, sizeof(float), stream);   // d_out is poisoned; ordered before walk
    hipLaunchKernelGGL(ctc_walk, dim3(BB), dim3(64), 0, stream,
                       lp, tokens, cqt, slen, out);
}

// Round 2
// 542.927 us; speedup vs baseline: 1.0820x; 1.0452x over previous
//
#include <hip/hip_runtime.h>
#include <math.h>

#define BB 32
#define TT 2048
#define VV 1024
#define SS 256
#define TCHUNK 4

// ---- async global->LDS: per-lane GLOBAL addr, wave-uniform LDS base + lane*size ----
__device__ __forceinline__ void async_ld16(const float* g, const float* l) {
    __builtin_amdgcn_global_load_lds(
        (const __attribute__((address_space(1))) void*)(uintptr_t)g,
        (__attribute__((address_space(3))) void*)(unsigned)(uintptr_t)l, 16, 0, 0);
}
__device__ __forceinline__ void async_ld4(const float* g, const float* l) {
    __builtin_amdgcn_global_load_lds(
        (const __attribute__((address_space(1))) void*)(uintptr_t)g,
        (__attribute__((address_space(3))) void*)(unsigned)(uintptr_t)l, 4, 0, 0);
}
// s_waitcnt simm16: [3:0]=vmcnt lo, [6:4]=expcnt, [11:8]=lgkmcnt, [15:14]=vmcnt hi
#define WAIT_VM27() __builtin_amdgcn_s_waitcnt(0x4F7B)  // vmcnt<=27 (main loop: 36 in flight)
#define WAIT_VM18() __builtin_amdgcn_s_waitcnt(0x4F72)  // vmcnt<=18 (tail: 27 in flight, no new issue)
#define WAIT_VM0()  __builtin_amdgcn_s_waitcnt(0x0F70)  // vmcnt<=0 drain

// ---- DPP wave_shr1: value from lane-1, lane0 -> 0. One VALU op, no lgkmcnt. ----
__device__ __forceinline__ float dpp_shr1_f(float x) {
    int r = __builtin_amdgcn_update_dpp(0, __float_as_int(x), 0x138, 0xF, 0xF, true);
    return __int_as_float(r);
}
__device__ __forceinline__ int dpp_shr1_i(int x) {
    return __builtin_amdgcn_update_dpp(0, x, 0x138, 0xF, 0xF, true);
}

// Kernel A: G[b][t][j] = (j<Sl)? exp(lp[b][t][tok_j]) : 0  (row = 256 floats)
//           Gbl[b][t]  = exp(lp[b][t][0])  (blank)
// 16384 blocks: the token gather runs here with massive memory-level parallelism
// (coalesced full-row staging to LDS, then LDS gather) instead of on one wave.
__global__ __launch_bounds__(256) void ctc_pre(const float* __restrict__ lp,
    const int* __restrict__ tokens, const int* __restrict__ cqt,
    const int* __restrict__ slen, float* __restrict__ G, float* __restrict__ Gbl,
    float* __restrict__ out)
{
    __shared__ __align__(16) float rows[TCHUNK][VV];
    __shared__ int toks[SS];
    const int tid = threadIdx.x;
    const int bx  = blockIdx.x;
    if (bx == 0 && tid == 0) out[0] = 0.f;   // zero the atomic accumulator (d_out is poisoned)
    const int nchunk = TT / TCHUNK;
    const int b  = bx / nchunk;
    const int t0 = (bx % nchunk) * TCHUNK;
    const int Tl = cqt[b];
    if (t0 >= Tl) return;                    // rows t>=Tl never read by walker (it clamps to Tl-1)
    const int Sl = slen[b];
    toks[tid] = tokens[b * SS + tid];
#pragma unroll
    for (int k = 0; k < TCHUNK; ++k) {       // stage up to 4 rows, one barrier total
        const int t = t0 + k;
        if (t < Tl)
            ((float4*)rows[k])[tid] = ((const float4*)(lp + ((size_t)b * TT + t) * VV))[tid];
    }
    __syncthreads();
#pragma unroll
    for (int k = 0; k < TCHUNK; ++k) {
        const int t = t0 + k;
        if (t >= Tl) break;                  // uniform across block
        float* gp = G + ((size_t)b * TT + t) * 256;
        gp[tid] = (tid < Sl) ? __expf(rows[k][toks[tid]]) : 0.f;
        if (tid == 0) Gbl[b * TT + t] = __expf(rows[k][0]);
    }
}

// Kernel B: serial CTC forward in linear domain, one wave per sample.
// Thread i owns states 8i..8i+7 (pairs j=4i..4i+3: even=blank, odd=token j).
// Per-lane power-of-2 exponent Etot; halo a7 crosses lanes via ONE DPP per step.
// Memory: 4-slot LDS ring filled by async global_load_lds (9 coalesced ops/chunk,
// depth-3 prefetch); LDS reads BATCHED into registers once per chunk behind the
// wait, so the serial chain never touches LDS latency per-step.
__global__ __launch_bounds__(64) void ctc_walk(const float* __restrict__ G,
    const float* __restrict__ Gbl, const int* __restrict__ tokens,
    const int* __restrict__ cqt, const int* __restrict__ slen, float* __restrict__ out)
{
    __shared__ __align__(16) float tokL[4][8 * 256];   // 32 KB: 4 slots x 8 rows x 1KB
    __shared__ __align__(16) float blkL[4][64];        // 1 KB: blank windows
    __shared__ float als[513];
    __shared__ int   aE[65];

    const int b    = blockIdx.x;
    const int lane = threadIdx.x;
    const int Tl   = cqt[b];
    const int Sl   = slen[b];
    const float* __restrict__ Gb   = G   + (size_t)b * TT * 256;
    const float* __restrict__ GblB = Gbl + (size_t)b * TT;
    const int j0 = lane * 4;
    const int* tb = tokens + b * SS;
    const int tm1 = (j0 == 0) ? 0 : tb[j0 - 1];
    const int q0 = tb[j0], q1 = tb[j0 + 1], q2 = tb[j0 + 2], q3 = tb[j0 + 3];
    const float m0 = (q0 != tm1) ? 1.f : 0.f;
    const float m1 = (q1 != q0)  ? 1.f : 0.f;
    const float m2 = (q2 != q1)  ? 1.f : 0.f;
    const float m3 = (q3 != q2)  ? 1.f : 0.f;
    const float lzm = (lane == 0) ? 0.f : 1.f;

    float a0=0.f,a1=0.f,a2=0.f,a3=0.f,a4=0.f,a5=0.f,a6=0.f,a7=0.f,aX=0.f;
    if (lane == 0) { a0 = GblB[0]; a1 = Gb[0]; }   // t=0 init
    int   Etot = 0;
    float sfac = lzm;

    // One chunk = 8 token rows (per-lane gaddr = row + lane*16B) + one blank window
    // (per-lane gaddr = GblB[clamp(tbase+lane)]) = 9 coalesced vm ops.
#define ISSUE(slot, tbase) do { \
    const float* lt = tokL[slot]; \
    _Pragma("unroll") \
    for (int k = 0; k < 8; ++k) { \
        int tt = (tbase) + k; tt = (tt < Tl) ? tt : (Tl - 1); \
        async_ld16(Gb + (size_t)tt * 256 + (lane << 2), lt + k * 256); \
    } \
    int tbk = (tbase) + lane; tbk = (tbk < Tl) ? tbk : (Tl - 1); \
    async_ld4(GblB + tbk, blkL[slot]); \
} while (0)

    // Batch all LDS->reg traffic for a chunk: 8x ds_read_b128 + 8x ds_read_b32.
#define LOADCHUNK(s) do { \
    _Pragma("unroll") \
    for (int k = 0; k < 8; ++k) { \
        pr[k] = ((const float4*)(tokL[s] + (k << 8)))[lane]; \
        pb[k] = blkL[s][k]; \
    } \
} while (0)

#define ONESTEP(P4, PB) do { \
    const float pb_ = (PB); \
    const float h1 = dpp_shr1_f(a7) * sfac; \
    const float n0 = pb_ * (a0 + h1); \
    const float n1 = (P4).x * (a1 + a0 + m0 * h1); \
    const float n2 = pb_ * (a2 + a1); \
    const float n3 = (P4).y * (a3 + a2 + m1 * a1); \
    const float n4 = pb_ * (a4 + a3); \
    const float n5 = (P4).z * (a5 + a4 + m2 * a3); \
    const float n6 = pb_ * (a6 + a5); \
    const float n7 = (P4).w * (a7 + a6 + m3 * a5); \
    aX = pb_ * (aX + a7); \
    a0=n0;a1=n1;a2=n2;a3=n3;a4=n4;a5=n5;a6=n6;a7=n7; \
} while (0)

    // Bit-trick renorm (mm never subnormal: p >= e^-16 over 4 steps keeps mm >= 2^-93).
#define RENORM_LOCAL() do { \
    float mm = fmaxf(fmaxf(fmaxf(a0,a1),fmaxf(a2,a3)), fmaxf(fmaxf(a4,a5),fmaxf(a6,a7))); \
    mm = fmaxf(mm, aX); \
    int ee = (__float_as_int(mm) >> 23) - 126; \
    ee = (mm > 0.f) ? ee : 0; \
    const float sc = __int_as_float((127 - ee) << 23); \
    a0*=sc;a1*=sc;a2*=sc;a3*=sc;a4*=sc;a5*=sc;a6*=sc;a7*=sc;aX*=sc; \
    Etot += ee; \
    int Ep = dpp_shr1_i(Etot); \
    if (mm == 0.f && lane > 0) Etot = Ep; \
    Ep = dpp_shr1_i(Etot); \
    if (mm == 0.f && lane > 0) Etot = Ep; \
    int dd = Ep - Etot; \
    dd = (dd < -126) ? -126 : ((dd > 100) ? 100 : dd); \
    sfac = __int_as_float((127 + dd) << 23) * lzm; \
} while (0)

    float4 pr[8];                                // static-index only -> registers
    float  pb[8];

    ISSUE(0, 1); ISSUE(1, 9); ISSUE(2, 17);      // depth-3 prefetch (27 vm ops in flight)
    int t = 1, slot = 0;
    while (t + 8 <= Tl) {                        // branchless full chunks
        const int ns = (slot + 3) & 3;
        ISSUE(ns, t + 24);                       // 36 in flight
        WAIT_VM27();                             // oldest chunk (this one) landed in LDS
        __builtin_amdgcn_sched_barrier(0);       // no ds_read may float above the wait
        LOADCHUNK(slot);                         // LDS latency paid once per chunk
#pragma unroll
        for (int k = 0; k < 8; ++k) {
            ONESTEP(pr[k], pb[k]);
            if (k == 3 || k == 7) RENORM_LOCAL();
        }
        t += 8; slot = (slot + 1) & 3;
    }
    if (t < Tl) {                                // tail chunk (nv in 1..7), already prefetched
        WAIT_VM18();                             // 27 in flight, nothing new issued: oldest 9 done
        __builtin_amdgcn_sched_barrier(0);
        LOADCHUNK(slot);
        const int nv = Tl - t;
#pragma unroll
        for (int k = 0; k < 8; ++k) {
            if (k < nv) ONESTEP(pr[k], pb[k]);
            if (k == 3 || k == 7) RENORM_LOCAL();
        }
    }
    WAIT_VM0();                                  // drain ring before epilogue/endpgm

    als[8 * lane + 0] = a0; als[8 * lane + 1] = a1;
    als[8 * lane + 2] = a2; als[8 * lane + 3] = a3;
    als[8 * lane + 4] = a4; als[8 * lane + 5] = a5;
    als[8 * lane + 6] = a6; als[8 * lane + 7] = a7;
    aE[lane] = Etot;
    if (lane == 63) { als[512] = aX; aE[64] = Etot; }
    __syncthreads();
    if (lane == 0) {
        const int sA = 2 * Sl, sB = 2 * Sl - 1;
        const float vA = als[sA], vB = als[sB];
        const int   eA = aE[sA >> 3], eB = aE[sB >> 3];
        int em;
        if (vA > 0.f && vB > 0.f) em = (eA > eB) ? eA : eB;
        else if (vA > 0.f)        em = eA;
        else if (vB > 0.f)        em = eB;
        else                      em = 0;
        const double s = ldexp((double)vA, eA - em) + ldexp((double)vB, eB - em);
        double loss = -(log(s) + (double)em * 0.6931471805599453);
        if (!(loss < 1e29)) loss = 0.0;
        atomicAdd(out, (float)(loss / ((double)Sl * (double)BB)));
    }
#undef ISSUE
#undef LOADCHUNK
#undef ONESTEP
#undef RENORM_LOCAL
}

extern "C" void kernel_launch(void* const* d_in, const int* in_sizes, int n_in,
                              void* d_out, int out_size, void* d_ws, size_t ws_size,
                              hipStream_t stream)
{
    const float* lp     = (const float*)d_in[0];
    const int*   tokens = (const int*)d_in[1];
    const int*   cqt    = (const int*)d_in[2];
    const int*   slen   = (const int*)d_in[3];
    float* out = (float*)d_out;
    float* G   = (float*)d_ws;                          // 32*2048*256 floats = 64 MiB
    float* Gbl = G + (size_t)BB * TT * 256;             // 32*2048 floats (walk clamps read-ahead)

    hipLaunchKernelGGL(ctc_pre,  dim3(BB * (TT / TCHUNK)), dim3(256), 0, stream,
                       lp, tokens, cqt, slen, G, Gbl, out);
    hipLaunchKernelGGL(ctc_walk, dim3(BB), dim3(64), 0, stream,
                       G, Gbl, tokens, cqt, slen, out);
}

// Round 3
// 519.064 us; speedup vs baseline: 1.1317x; 1.0460x over previous
//
#include <hip/hip_runtime.h>
#include <math.h>

#define BB 32
#define TT 2048
#define VV 1024
#define SS 256
#define TCHUNK 4
#define NSLOT 6

// ---- async global->LDS: per-lane GLOBAL addr, wave-uniform LDS base + lane*size ----
__device__ __forceinline__ void async_ld16(const float* g, const float* l) {
    __builtin_amdgcn_global_load_lds(
        (const __attribute__((address_space(1))) void*)(uintptr_t)g,
        (__attribute__((address_space(3))) void*)(unsigned)(uintptr_t)l, 16, 0, 0);
}
__device__ __forceinline__ void async_ld4(const float* g, const float* l) {
    __builtin_amdgcn_global_load_lds(
        (const __attribute__((address_space(1))) void*)(uintptr_t)g,
        (__attribute__((address_space(3))) void*)(unsigned)(uintptr_t)l, 4, 0, 0);
}
// s_waitcnt simm16: [3:0]=vmcnt lo, [6:4]=expcnt, [11:8]=lgkmcnt, [15:14]=vmcnt hi
#define WAIT_VM0() __builtin_amdgcn_s_waitcnt(0x0F70)   // vmcnt<=0 (producer drains own ops)

// ---- DPP wave_shr1: value from lane-1, lane0 -> 0. One VALU op, no lgkmcnt. ----
__device__ __forceinline__ float dpp_shr1_f(float x) {
    int r = __builtin_amdgcn_update_dpp(0, __float_as_int(x), 0x138, 0xF, 0xF, true);
    return __int_as_float(r);
}
__device__ __forceinline__ int dpp_shr1_i(int x) {
    return __builtin_amdgcn_update_dpp(0, x, 0x138, 0xF, 0xF, true);
}

// Kernel A: G[b][t][j] = (j<Sl)? exp(lp[b][t][tok_j]) : 0  (row = 256 floats)
//           Gbl[b][t]  = exp(lp[b][t][0])  (blank)
__global__ __launch_bounds__(256) void ctc_pre(const float* __restrict__ lp,
    const int* __restrict__ tokens, const int* __restrict__ cqt,
    const int* __restrict__ slen, float* __restrict__ G, float* __restrict__ Gbl,
    float* __restrict__ out)
{
    __shared__ __align__(16) float rows[TCHUNK][VV];
    __shared__ int toks[SS];
    const int tid = threadIdx.x;
    const int bx  = blockIdx.x;
    if (bx == 0 && tid == 0) out[0] = 0.f;   // zero the atomic accumulator (d_out is poisoned)
    const int nchunk = TT / TCHUNK;
    const int b  = bx / nchunk;
    const int t0 = (bx % nchunk) * TCHUNK;
    const int Tl = cqt[b];
    if (t0 >= Tl) return;                    // rows t>=Tl never read (walker clamps to Tl-1)
    const int Sl = slen[b];
    toks[tid] = tokens[b * SS + tid];
#pragma unroll
    for (int k = 0; k < TCHUNK; ++k) {       // stage up to 4 rows, one barrier total
        const int t = t0 + k;
        if (t < Tl)
            ((float4*)rows[k])[tid] = ((const float4*)(lp + ((size_t)b * TT + t) * VV))[tid];
    }
    __syncthreads();
#pragma unroll
    for (int k = 0; k < TCHUNK; ++k) {
        const int t = t0 + k;
        if (t >= Tl) break;                  // uniform across block
        float* gp = G + ((size_t)b * TT + t) * 256;
        gp[tid] = (tid < Sl) ? __expf(rows[k][toks[tid]]) : 0.f;
        if (tid == 0) Gbl[b * TT + t] = __expf(rows[k][0]);
    }
}

// Kernel B: producer-consumer CTC walk. 4 waves per block:
//   wave 0  = serial walker (identical arithmetic to verified round-2 kernel);
//   waves 1-3 = fetchers: chunk c (stride 3) -> 9 global_load_lds into ring slot
//               c%6, own vmcnt(0), then LDS ready-flag. Walker never waits on
//               vmcnt; it polls the flag (steady state: data ready, 1 poll).
__global__ __launch_bounds__(256) void ctc_walk(const float* __restrict__ G,
    const float* __restrict__ Gbl, const int* __restrict__ tokens,
    const int* __restrict__ cqt, const int* __restrict__ slen, float* __restrict__ out)
{
    __shared__ __align__(16) float tokL[NSLOT][8 * 256];   // 48 KB ring: 6 slots x 8 rows x 1KB
    __shared__ __align__(16) float blkL[NSLOT][64];        // blank windows
    __shared__ float als[513];
    __shared__ int   aE[65];
    __shared__ int   ready[NSLOT];
    __shared__ int   prog;

    const int b    = blockIdx.x;
    const int tid  = threadIdx.x;
    const int wid  = tid >> 6;
    const int lane = tid & 63;
    const int Tl   = cqt[b];
    const float* __restrict__ Gb   = G   + (size_t)b * TT * 256;
    const float* __restrict__ GblB = Gbl + (size_t)b * TT;

    if (tid < NSLOT) ready[tid] = -1;
    if (tid == NSLOT) prog = -1;
    __syncthreads();                          // only barrier; all 4 waves reach it once

    const int NC = (Tl + 6) >> 3;             // ceil((Tl-1)/8) chunks; t0(c) = 1 + 8c
    volatile int* vready = ready;
    volatile int* vprog  = &prog;

    if (wid != 0) {
        // ---------------- producer waves (1..3) ----------------
        for (int c = wid - 1; c < NC; c += 3) {
            const int slot = c % NSLOT;
            while (*vprog < c - NSLOT) {}     // slot's previous occupant consumed?
            __builtin_amdgcn_sched_barrier(0);
            asm volatile("" ::: "memory");
            const int tbase = 1 + (c << 3);
            const float* lt = tokL[slot];
#pragma unroll
            for (int k = 0; k < 8; ++k) {
                int tt = tbase + k; tt = (tt < Tl) ? tt : (Tl - 1);
                async_ld16(Gb + (size_t)tt * 256 + (lane << 2), lt + k * 256);
            }
            int tbk = tbase + lane; tbk = (tbk < Tl) ? tbk : (Tl - 1);
            async_ld4(GblB + tbk, blkL[slot]);
            WAIT_VM0();                       // own 9 ops landed in LDS
            __builtin_amdgcn_sched_barrier(0);
            asm volatile("" ::: "memory");
            vready[slot] = c;                 // publish
        }
        return;                               // producers exit; no further barriers anywhere
    }

    // ---------------- walker wave (0) ----------------
    const int Sl = slen[b];
    const int j0 = lane * 4;
    const int* tb = tokens + b * SS;
    const int tm1 = (j0 == 0) ? 0 : tb[j0 - 1];
    const int q0 = tb[j0], q1 = tb[j0 + 1], q2 = tb[j0 + 2], q3 = tb[j0 + 3];
    const float m0 = (q0 != tm1) ? 1.f : 0.f;
    const float m1 = (q1 != q0)  ? 1.f : 0.f;
    const float m2 = (q2 != q1)  ? 1.f : 0.f;
    const float m3 = (q3 != q2)  ? 1.f : 0.f;
    const float lzm = (lane == 0) ? 0.f : 1.f;

    float a0=0.f,a1=0.f,a2=0.f,a3=0.f,a4=0.f,a5=0.f,a6=0.f,a7=0.f,aX=0.f;
    if (lane == 0) { a0 = GblB[0]; a1 = Gb[0]; }   // t=0 init
    int   Etot = 0;
    float sfac = lzm;

#define LOADCHUNK(s) do { \
    _Pragma("unroll") \
    for (int k = 0; k < 8; ++k) { \
        pr[k] = ((const float4*)(tokL[s] + (k << 8)))[lane]; \
        pb[k] = blkL[s][k]; \
    } \
} while (0)

#define ONESTEP(P4, PB) do { \
    const float pb_ = (PB); \
    const float h1 = dpp_shr1_f(a7) * sfac; \
    const float n0 = pb_ * (a0 + h1); \
    const float n1 = (P4).x * (a1 + a0 + m0 * h1); \
    const float n2 = pb_ * (a2 + a1); \
    const float n3 = (P4).y * (a3 + a2 + m1 * a1); \
    const float n4 = pb_ * (a4 + a3); \
    const float n5 = (P4).z * (a5 + a4 + m2 * a3); \
    const float n6 = pb_ * (a6 + a5); \
    const float n7 = (P4).w * (a7 + a6 + m3 * a5); \
    aX = pb_ * (aX + a7); \
    a0=n0;a1=n1;a2=n2;a3=n3;a4=n4;a5=n5;a6=n6;a7=n7; \
} while (0)

    // Bit-trick renorm (mm never subnormal: p >= e^-16 over 4 steps keeps mm >= 2^-93).
#define RENORM_LOCAL() do { \
    float mm = fmaxf(fmaxf(fmaxf(a0,a1),fmaxf(a2,a3)), fmaxf(fmaxf(a4,a5),fmaxf(a6,a7))); \
    mm = fmaxf(mm, aX); \
    int ee = (__float_as_int(mm) >> 23) - 126; \
    ee = (mm > 0.f) ? ee : 0; \
    const float sc = __int_as_float((127 - ee) << 23); \
    a0*=sc;a1*=sc;a2*=sc;a3*=sc;a4*=sc;a5*=sc;a6*=sc;a7*=sc;aX*=sc; \
    Etot += ee; \
    int Ep = dpp_shr1_i(Etot); \
    if (mm == 0.f && lane > 0) Etot = Ep; \
    Ep = dpp_shr1_i(Etot); \
    if (mm == 0.f && lane > 0) Etot = Ep; \
    int dd = Ep - Etot; \
    dd = (dd < -126) ? -126 : ((dd > 100) ? 100 : dd); \
    sfac = __int_as_float((127 + dd) << 23) * lzm; \
} while (0)

    float4 pr[8];                                // static-index only -> registers
    float  pb[8];

    const int F = (Tl - 1) >> 3;                 // full chunks
    for (int c = 0; c < F; ++c) {
        const int slot = c % NSLOT;
        while (vready[slot] < c) {}              // steady state: one poll
        __builtin_amdgcn_sched_barrier(0);       // no ds_read may float above the flag
        asm volatile("" ::: "memory");
        LOADCHUNK(slot);                         // LDS latency paid once per chunk
        asm volatile("" ::: "memory");
        *vprog = c;                              // slot reusable (data now in regs/queue)
#pragma unroll
        for (int k = 0; k < 8; ++k) {
            ONESTEP(pr[k], pb[k]);
            if (k == 3 || k == 7) RENORM_LOCAL();
        }
    }
    if (F < NC) {                                // tail chunk (nv in 1..7)
        const int slot = F % NSLOT;
        while (vready[slot] < F) {}
        __builtin_amdgcn_sched_barrier(0);
        asm volatile("" ::: "memory");
        LOADCHUNK(slot);
        asm volatile("" ::: "memory");
        *vprog = F;
        const int nv = (Tl - 1) - (F << 3);
#pragma unroll
        for (int k = 0; k < 8; ++k) {
            if (k < nv) ONESTEP(pr[k], pb[k]);
            if (k == 3 || k == 7) RENORM_LOCAL();
        }
    }

    als[8 * lane + 0] = a0; als[8 * lane + 1] = a1;
    als[8 * lane + 2] = a2; als[8 * lane + 3] = a3;
    als[8 * lane + 4] = a4; als[8 * lane + 5] = a5;
    als[8 * lane + 6] = a6; als[8 * lane + 7] = a7;
    aE[lane] = Etot;
    if (lane == 63) { als[512] = aX; aE[64] = Etot; }
    asm volatile("s_waitcnt lgkmcnt(0)" ::: "memory");   // same-wave LDS RAW; no barrier
    if (lane == 0) {
        const int sA = 2 * Sl, sB = 2 * Sl - 1;
        const float vA = als[sA], vB = als[sB];
        const int   eA = aE[sA >> 3], eB = aE[sB >> 3];
        int em;
        if (vA > 0.f && vB > 0.f) em = (eA > eB) ? eA : eB;
        else if (vA > 0.f)        em = eA;
        else if (vB > 0.f)        em = eB;
        else                      em = 0;
        const double s = ldexp((double)vA, eA - em) + ldexp((double)vB, eB - em);
        double loss = -(log(s) + (double)em * 0.6931471805599453);
        if (!(loss < 1e29)) loss = 0.0;
        atomicAdd(out, (float)(loss / ((double)Sl * (double)BB)));
    }
#undef LOADCHUNK
#undef ONESTEP
#undef RENORM_LOCAL
}

extern "C" void kernel_launch(void* const* d_in, const int* in_sizes, int n_in,
                              void* d_out, int out_size, void* d_ws, size_t ws_size,
                              hipStream_t stream)
{
    const float* lp     = (const float*)d_in[0];
    const int*   tokens = (const int*)d_in[1];
    const int*   cqt    = (const int*)d_in[2];
    const int*   slen   = (const int*)d_in[3];
    float* out = (float*)d_out;
    float* G   = (float*)d_ws;                          // 32*2048*256 floats = 64 MiB
    float* Gbl = G + (size_t)BB * TT * 256;             // 32*2048 floats (walk clamps read-ahead)

    hipLaunchKernelGGL(ctc_pre,  dim3(BB * (TT / TCHUNK)), dim3(256), 0, stream,
                       lp, tokens, cqt, slen, G, Gbl, out);
    hipLaunchKernelGGL(ctc_walk, dim3(BB), dim3(256), 0, stream,
                       G, Gbl, tokens, cqt, slen, out);
}